// Round 7
// baseline (147.102 us; speedup 1.0000x reference)
//
#include <hip/hip_runtime.h>
#include <stdint.h>
#include <stddef.h>

typedef _Float16 f16_t;
typedef _Float16 f16x4 __attribute__((ext_vector_type(4)));
typedef _Float16 f16x8 __attribute__((ext_vector_type(8)));
typedef float f32x4 __attribute__((ext_vector_type(4)));

#define AS_G __attribute__((address_space(1)))
#define AS_L __attribute__((address_space(3)))

__device__ __forceinline__ void gload_lds16(const void* g, void* l) {
  __builtin_amdgcn_global_load_lds((AS_G void*)g, (AS_L void*)l, 16, 0, 0);
}

#define FENCE() asm volatile("" ::: "memory")
#define BARX()                            \
  do {                                    \
    FENCE();                              \
    __builtin_amdgcn_s_barrier();         \
    FENCE();                              \
  } while (0)
#define VMCNT(n) asm volatile("s_waitcnt vmcnt(" #n ")" ::: "memory")

// ---------------- merged prep + xavg kernel ----------------
// blocks [0,1024): Wo f32->f16 cvt; [1024,2048): Wv transpose+cvt;
// [2048,3072): bconst; [3072,7168): xavg 3-tap (8 rows/block)

__global__ __launch_bounds__(256) void prep_xavg_kernel(
    const float* __restrict__ X, const float* __restrict__ Wo,
    const float* __restrict__ Wv, const float* __restrict__ bv,
    const float* __restrict__ bo, const float* __restrict__ nw, int Kw,
    f16_t* __restrict__ Wo_h, f16_t* __restrict__ WvT, float* __restrict__ bc,
    f16_t* __restrict__ Xavg) {
  __shared__ float smem[32 * 33];
  const int b = blockIdx.x;
  const int t = threadIdx.x;
  if (b >= 3072) {
    const int T = 4096, D = 1024;
    const int base = (b - 3072) * 8;
    const int t0 = base & (T - 1);
    const int col = t * 4;
    const float w0 = nw[0], w1 = nw[1], w2 = nw[2];
    const float* xb = X + (size_t)base * D + col;
    f32x4 va = *(const f32x4*)(xb + (t0 == 0 ? 0 : -D));
    f32x4 vb = *(const f32x4*)(xb);
    f16_t* ob = Xavg + (size_t)base * D + col;
#pragma unroll
    for (int g = 0; g < 8; ++g) {
      f32x4 vc;
      if (t0 + g == T - 1) vc = vb;
      else vc = *(const f32x4*)(xb + (size_t)(g + 1) * D);
      f32x4 y = w0 * va + w1 * vb + w2 * vc;
      f16x4 o;
      o.x = (f16_t)y.x; o.y = (f16_t)y.y; o.z = (f16_t)y.z; o.w = (f16_t)y.w;
      *(f16x4*)(ob + (size_t)g * D) = o;
      va = vb;
      vb = vc;
    }
  } else if (b < 1024) {
    const int i = b * 256 + t;
    f32x4 v = ((const f32x4*)Wo)[i];
    f16x4 o;
    o.x = (f16_t)v.x; o.y = (f16_t)v.y; o.z = (f16_t)v.z; o.w = (f16_t)v.w;
    ((f16x4*)Wo_h)[i] = o;
  } else if (b < 2048) {
    const int i = b - 1024;
    const int bx = i & 31, by = i >> 5;
    const int tx = t & 31, ty = t >> 5;
#pragma unroll
    for (int k = 0; k < 32; k += 8)
      smem[(ty + k) * 33 + tx] = Wv[(size_t)(by * 32 + ty + k) * 1024 + bx * 32 + tx];
    __syncthreads();
#pragma unroll
    for (int k = 0; k < 32; k += 8)
      WvT[(size_t)(bx * 32 + ty + k) * 1024 + by * 32 + tx] = (f16_t)smem[tx * 33 + ty + k];
  } else {
    const int e = b - 2048;
    float sw = 0.f;
    for (int k = 0; k < Kw; ++k) sw += nw[k];
    float p = 0.f;
    for (int d = t; d < 1024; d += 256) p += Wo[(size_t)e * 1024 + d] * bv[d];
    smem[t] = p;
    __syncthreads();
    for (int s = 128; s > 0; s >>= 1) {
      if (t < s) smem[t] += smem[t + s];
      __syncthreads();
    }
    if (t == 0) bc[e] = sw * smem[0] + bo[e];
  }
}

// ---------------- 128^2 GEMM (small 1024^3 WcT GEMM) ----------------

template <typename OutT, bool BIAS>
__global__ __launch_bounds__(256) void gemm_bt_kernel(const f16_t* __restrict__ A,
                                                      const f16_t* __restrict__ Bt,
                                                      OutT* __restrict__ C,
                                                      const float* __restrict__ bias,
                                                      int M, int N, int K) {
  __shared__ __align__(16) f16_t sA[128 * 32];
  __shared__ __align__(16) f16_t sB[128 * 32];
  const int tid = threadIdx.x;
  const int l = tid & 63;
  const int w = tid >> 6;
  const int wr = w >> 1;
  const int wc = w & 1;
  const int nMT = M >> 7;
  const int bid = blockIdx.x;
  const int mt = bid % nMT;
  const int nt = bid / nMT;
  const int m0 = mt << 7;
  const int n0 = nt << 7;

  const int srow = (w << 4) + (l >> 2);
  const int scol = (l & 3) << 3;
  const size_t aoff0 = (size_t)(m0 + srow) * K + scol;
  const size_t boff0 = (size_t)(n0 + srow) * K + scol;
  f16_t* ldsA = sA + (w << 9);
  f16_t* ldsB = sB + (w << 9);

  f32x4 acc[4][4];
#pragma unroll
  for (int i = 0; i < 4; ++i)
#pragma unroll
    for (int j = 0; j < 4; ++j) acc[i][j] = f32x4{0.f, 0.f, 0.f, 0.f};

  const int ka = (l >> 4) << 3;
  const int ar = (wr << 6) + (l & 15);
  const int br = (wc << 6) + (l & 15);

  const int nK = K >> 5;
  for (int kt = 0; kt < nK; ++kt) {
    const int kb = kt << 5;
    gload_lds16(A + aoff0 + kb, ldsA);
    gload_lds16(A + aoff0 + ((size_t)K << 6) + kb, ldsA + 2048);
    gload_lds16(Bt + boff0 + kb, ldsB);
    gload_lds16(Bt + boff0 + ((size_t)K << 6) + kb, ldsB + 2048);
    __syncthreads();
    f16x8 af[4], bfr[4];
#pragma unroll
    for (int m = 0; m < 4; ++m) af[m] = *(const f16x8*)(sA + ((ar + (m << 4)) << 5) + ka);
#pragma unroll
    for (int n = 0; n < 4; ++n) bfr[n] = *(const f16x8*)(sB + ((br + (n << 4)) << 5) + ka);
#pragma unroll
    for (int m = 0; m < 4; ++m)
#pragma unroll
      for (int n = 0; n < 4; ++n)
        acc[m][n] = __builtin_amdgcn_mfma_f32_16x16x32_f16(af[m], bfr[n], acc[m][n], 0, 0, 0);
    __syncthreads();
  }

  const int orow = (l >> 4) << 2;
  const int ocol = l & 15;
#pragma unroll
  for (int n = 0; n < 4; ++n) {
    const int gn = n0 + (wc << 6) + (n << 4) + ocol;
    const float bs = BIAS ? bias[gn] : 0.f;
#pragma unroll
    for (int m = 0; m < 4; ++m) {
      const int gm = m0 + (wr << 6) + (m << 4) + orow;
#pragma unroll
      for (int j = 0; j < 4; ++j) {
        C[(size_t)(gm + j) * N + gn] = (OutT)(acc[m][n][j] + bs);
      }
    }
  }
}

// ---------------- 256^2 GEMM v5: BK=32, ring-4, cross-step register frag dbuf ----------------
// C[M][N] = A[M][K]*Bt[N][K]^T + bias. 8 waves (2Mx4N), 16x16x32 MFMA.
// Per step t: stage tile t+3 (4 gload/wave); prefetch frags of tile t+1 into the
// spare register set (12 ds_read_b128, no wait); 32 MFMAs on current set; VMCNT(4);
// barrier. Ordering: VMCNT(4) at end of step t (after issuing stage t+3) leaves only
// stage t+3 outstanding -> tile t+2 certified landed for every wave before the barrier
// that precedes step t+1's prefetch of tile t+2. Granule reuse: stage t+3 writes
// granule (t-1)&3, last LDS-read during step t-2's prefetch; all waves passed the
// end-of-step-(t-1) barrier. Tail: stages clamped to tile nK-1 (rewrites identical
// bytes -> race-free); final prefetch reads a dead granule (uniform, unused).

__device__ __forceinline__ void stage256(const f16_t* __restrict__ g, int K,
                                         f16_t* ldsOp, int w, int l) {
#pragma unroll
  for (int i = 0; i < 2; ++i) {
    const int f = i * 512 + w * 64 + l;
    const int row = f >> 2;
    const int ch = f & 3;
    const int col = ((ch ^ ((row >> 1) & 3)) << 3);  // swizzled source column (f16)
    gload_lds16(g + (size_t)row * K + col, ldsOp + i * 4096 + w * 512);
  }
}

__global__ __launch_bounds__(512, 2) void gemm256_kernel(const f16_t* __restrict__ A,
                                                         const f16_t* __restrict__ Bt,
                                                         float* __restrict__ C,
                                                         const float* __restrict__ bias,
                                                         int M, int N, int K) {
  __shared__ __align__(16) f16_t lds[4 * 16384];  // 4 granules x (A 16KB + B 16KB)
  const int tid = threadIdx.x;
  const int l = tid & 63;
  const int w = tid >> 6;
  const int wr = w >> 2;
  const int wc = w & 3;
  const int lr = l & 15;
  const int q = l >> 4;

  const int cpx = (int)gridDim.x >> 3;
  const int swzb = ((int)blockIdx.x & 7) * cpx + ((int)blockIdx.x >> 3);
  const int nNT = N >> 8;
  const int mt = swzb / nNT;
  const int nt = swzb % nNT;
  const int m0 = mt << 8;
  const int n0 = nt << 8;

  const f16_t* Apanel = A + (size_t)m0 * K;
  const f16_t* Bpanel = Bt + (size_t)n0 * K;
  const int sw = (q ^ ((lr >> 1) & 3)) << 3;  // lane-constant swizzled k-offset (f16)

  f32x4 acc[8][4];
#pragma unroll
  for (int m = 0; m < 8; ++m)
#pragma unroll
    for (int n = 0; n < 4; ++n) acc[m][n] = f32x4{0.f, 0.f, 0.f, 0.f};

  const int nK = K >> 5;  // 32 (even)

  // prologue: stage tiles 0,1,2 into granules 0,1,2 (12 vmem instrs/wave)
  for (int t = 0; t < 3; ++t) {
    f16_t* buf = lds + (t & 3) * 16384;
    stage256(Apanel + (t << 5), K, buf, w, l);
    stage256(Bpanel + (t << 5), K, buf + 8192, w, l);
  }
  VMCNT(4);  // tiles 0,1 landed (stage 2 = 4 instrs may fly)
  BARX();

  f16x8 af0[4], ag0[4], bf0[4], af1[4], ag1[4], bf1[4];

#define READSET(SUF, GRAN)                                                        \
  do {                                                                            \
    const f16_t* gA_ = lds + (size_t)(GRAN) * 16384;                              \
    const f16_t* gB_ = gA_ + 8192;                                                \
    _Pragma("unroll") for (int n_ = 0; n_ < 4; ++n_)                              \
      bf##SUF[n_] = *(const f16x8*)(gB_ + (((wc << 6) + (n_ << 4) + lr) << 5) + sw); \
    _Pragma("unroll") for (int m_ = 0; m_ < 4; ++m_) {                            \
      af##SUF[m_] = *(const f16x8*)(gA_ + (((wr << 7) + (m_ << 4) + lr) << 5) + sw); \
      ag##SUF[m_] = *(const f16x8*)(gA_ + (((wr << 7) + 64 + (m_ << 4) + lr) << 5) + sw); \
    }                                                                             \
  } while (0)

#define MFMASET(SUF)                                                              \
  do {                                                                            \
    __builtin_amdgcn_s_setprio(1);                                                \
    _Pragma("unroll") for (int m_ = 0; m_ < 4; ++m_)                              \
      _Pragma("unroll") for (int n_ = 0; n_ < 4; ++n_)                            \
        acc[m_][n_] = __builtin_amdgcn_mfma_f32_16x16x32_f16(                     \
            af##SUF[m_], bf##SUF[n_], acc[m_][n_], 0, 0, 0);                      \
    _Pragma("unroll") for (int m_ = 0; m_ < 4; ++m_)                              \
      _Pragma("unroll") for (int n_ = 0; n_ < 4; ++n_)                            \
        acc[m_ + 4][n_] = __builtin_amdgcn_mfma_f32_16x16x32_f16(                 \
            ag##SUF[m_], bf##SUF[n_], acc[m_ + 4][n_], 0, 0, 0);                  \
    __builtin_amdgcn_s_setprio(0);                                                \
  } while (0)

#define STAGESTEP(TT)                                                             \
  do {                                                                            \
    const int tn_ = (TT) < nK ? (TT) : (nK - 1);                                  \
    f16_t* g_ = lds + (tn_ & 3) * 16384;                                          \
    stage256(Apanel + ((size_t)tn_ << 5), K, g_, w, l);                           \
    stage256(Bpanel + ((size_t)tn_ << 5), K, g_ + 8192, w, l);                    \
  } while (0)

  READSET(0, 0);  // frags of tile 0

  for (int t = 0; t < nK; t += 2) {
    // step t: consume set0 (tile t), prefetch set1 (tile t+1)
    STAGESTEP(t + 3);
    READSET(1, (t + 1) & 3);
    MFMASET(0);
    VMCNT(4);  // only stage t+3 outstanding -> tile t+2 certified for next prefetch
    BARX();
    // step t+1: consume set1 (tile t+1), prefetch set0 (tile t+2)
    STAGESTEP(t + 4);
    READSET(0, (t + 2) & 3);  // at t=nK-2: dead granule (uniform, unused)
    MFMASET(1);
    VMCNT(4);
    BARX();
  }
#undef READSET
#undef MFMASET
#undef STAGESTEP

  // epilogue: C/D layout col = l&15, row = (l>>4)*4 + j
  float bs[4];
#pragma unroll
  for (int n = 0; n < 4; ++n) bs[n] = bias[n0 + (wc << 6) + (n << 4) + lr];
#pragma unroll
  for (int m = 0; m < 8; ++m) {
    const int gm = m0 + (wr << 7) + (m << 4) + (q << 2);
#pragma unroll
    for (int j = 0; j < 4; ++j) {
      float* Crow = C + (size_t)(gm + j) * N + n0 + (wc << 6) + lr;
#pragma unroll
      for (int n = 0; n < 4; ++n) Crow[n << 4] = acc[m][n][j] + bs[n];
    }
  }
}

// ---------------- launch ----------------

extern "C" void kernel_launch(void* const* d_in, const int* in_sizes, int n_in,
                              void* d_out, int out_size, void* d_ws, size_t ws_size,
                              hipStream_t stream) {
  const float* x = (const float*)d_in[0];    // [8,4096,1024]
  const float* Wv = (const float*)d_in[1];   // [1024,1024]
  const float* bv = (const float*)d_in[2];   // [1024]
  const float* Wo = (const float*)d_in[3];   // [1024,1024]
  const float* bo = (const float*)d_in[4];   // [1024]
  const float* nw = (const float*)d_in[5];   // [3]
  float* out = (float*)d_out;

  char* ws = (char*)d_ws;
  f16_t* Wo_h = (f16_t*)(ws);                  // 2 MB
  f16_t* WvT  = (f16_t*)(ws + (2u << 20));     // 2 MB
  f16_t* WcT  = (f16_t*)(ws + (4u << 20));     // 2 MB (WcT = Wo @ Wv, [e][c])
  float* bc   = (float*)(ws + (6u << 20));     // 4 KB
  f16_t* Xavg = (f16_t*)(ws + (8u << 20));     // 64 MB

  prep_xavg_kernel<<<dim3(7168), dim3(256), 0, stream>>>(
      x, Wo, Wv, bv, bo, nw, in_sizes[5], Wo_h, WvT, bc, Xavg);
  gemm_bt_kernel<f16_t, false><<<dim3(64), dim3(256), 0, stream>>>(
      Wo_h, WvT, WcT, (const float*)nullptr, 1024, 1024, 1024);
  gemm256_kernel<<<dim3(512), dim3(512), 0, stream>>>(
      Xavg, WcT, out, bc, 32768, 1024, 1024);
}

// Round 8
// 145.762 us; speedup vs baseline: 1.0092x; 1.0092x over previous
//
#include <hip/hip_runtime.h>
#include <stdint.h>
#include <stddef.h>

typedef _Float16 f16_t;
typedef _Float16 f16x4 __attribute__((ext_vector_type(4)));
typedef _Float16 f16x8 __attribute__((ext_vector_type(8)));
typedef float f32x4 __attribute__((ext_vector_type(4)));

#define AS_G __attribute__((address_space(1)))
#define AS_L __attribute__((address_space(3)))

__device__ __forceinline__ void gload_lds16(const void* g, void* l) {
  __builtin_amdgcn_global_load_lds((AS_G void*)g, (AS_L void*)l, 16, 0, 0);
}

#define FENCE() asm volatile("" ::: "memory")
#define BARX()                            \
  do {                                    \
    FENCE();                              \
    __builtin_amdgcn_s_barrier();         \
    FENCE();                              \
  } while (0)
#define VMCNT(n) asm volatile("s_waitcnt vmcnt(" #n ")" ::: "memory")
#define LGKM0() asm volatile("s_waitcnt lgkmcnt(0)" ::: "memory")
#if defined(__HIP_DEVICE_COMPILE__)
#define SCHEDB0() __builtin_amdgcn_sched_barrier(0)
#else
#define SCHEDB0()
#endif

// ---------------- merged prep + xavg kernel ----------------
// blocks [0,1024): Wo f32->f16 cvt; [1024,2048): Wv transpose+cvt;
// [2048,3072): bconst; [3072,7168): xavg 3-tap (8 rows/block)

__global__ __launch_bounds__(256) void prep_xavg_kernel(
    const float* __restrict__ X, const float* __restrict__ Wo,
    const float* __restrict__ Wv, const float* __restrict__ bv,
    const float* __restrict__ bo, const float* __restrict__ nw, int Kw,
    f16_t* __restrict__ Wo_h, f16_t* __restrict__ WvT, float* __restrict__ bc,
    f16_t* __restrict__ Xavg) {
  __shared__ float smem[32 * 33];
  const int b = blockIdx.x;
  const int t = threadIdx.x;
  if (b >= 3072) {
    const int T = 4096, D = 1024;
    const int base = (b - 3072) * 8;
    const int t0 = base & (T - 1);
    const int col = t * 4;
    const float w0 = nw[0], w1 = nw[1], w2 = nw[2];
    const float* xb = X + (size_t)base * D + col;
    f32x4 va = *(const f32x4*)(xb + (t0 == 0 ? 0 : -D));
    f32x4 vb = *(const f32x4*)(xb);
    f16_t* ob = Xavg + (size_t)base * D + col;
#pragma unroll
    for (int g = 0; g < 8; ++g) {
      f32x4 vc;
      if (t0 + g == T - 1) vc = vb;
      else vc = *(const f32x4*)(xb + (size_t)(g + 1) * D);
      f32x4 y = w0 * va + w1 * vb + w2 * vc;
      f16x4 o;
      o.x = (f16_t)y.x; o.y = (f16_t)y.y; o.z = (f16_t)y.z; o.w = (f16_t)y.w;
      *(f16x4*)(ob + (size_t)g * D) = o;
      va = vb;
      vb = vc;
    }
  } else if (b < 1024) {
    const int i = b * 256 + t;
    f32x4 v = ((const f32x4*)Wo)[i];
    f16x4 o;
    o.x = (f16_t)v.x; o.y = (f16_t)v.y; o.z = (f16_t)v.z; o.w = (f16_t)v.w;
    ((f16x4*)Wo_h)[i] = o;
  } else if (b < 2048) {
    const int i = b - 1024;
    const int bx = i & 31, by = i >> 5;
    const int tx = t & 31, ty = t >> 5;
#pragma unroll
    for (int k = 0; k < 32; k += 8)
      smem[(ty + k) * 33 + tx] = Wv[(size_t)(by * 32 + ty + k) * 1024 + bx * 32 + tx];
    __syncthreads();
#pragma unroll
    for (int k = 0; k < 32; k += 8)
      WvT[(size_t)(bx * 32 + ty + k) * 1024 + by * 32 + tx] = (f16_t)smem[tx * 33 + ty + k];
  } else {
    const int e = b - 2048;
    float sw = 0.f;
    for (int k = 0; k < Kw; ++k) sw += nw[k];
    float p = 0.f;
    for (int d = t; d < 1024; d += 256) p += Wo[(size_t)e * 1024 + d] * bv[d];
    smem[t] = p;
    __syncthreads();
    for (int s = 128; s > 0; s >>= 1) {
      if (t < s) smem[t] += smem[t + s];
      __syncthreads();
    }
    if (t == 0) bc[e] = sw * smem[0] + bo[e];
  }
}

// ---------------- 128^2 GEMM (small 1024^3 WcT GEMM) ----------------

template <typename OutT, bool BIAS>
__global__ __launch_bounds__(256) void gemm_bt_kernel(const f16_t* __restrict__ A,
                                                      const f16_t* __restrict__ Bt,
                                                      OutT* __restrict__ C,
                                                      const float* __restrict__ bias,
                                                      int M, int N, int K) {
  __shared__ __align__(16) f16_t sA[128 * 32];
  __shared__ __align__(16) f16_t sB[128 * 32];
  const int tid = threadIdx.x;
  const int l = tid & 63;
  const int w = tid >> 6;
  const int wr = w >> 1;
  const int wc = w & 1;
  const int nMT = M >> 7;
  const int bid = blockIdx.x;
  const int mt = bid % nMT;
  const int nt = bid / nMT;
  const int m0 = mt << 7;
  const int n0 = nt << 7;

  const int srow = (w << 4) + (l >> 2);
  const int scol = (l & 3) << 3;
  const size_t aoff0 = (size_t)(m0 + srow) * K + scol;
  const size_t boff0 = (size_t)(n0 + srow) * K + scol;
  f16_t* ldsA = sA + (w << 9);
  f16_t* ldsB = sB + (w << 9);

  f32x4 acc[4][4];
#pragma unroll
  for (int i = 0; i < 4; ++i)
#pragma unroll
    for (int j = 0; j < 4; ++j) acc[i][j] = f32x4{0.f, 0.f, 0.f, 0.f};

  const int ka = (l >> 4) << 3;
  const int ar = (wr << 6) + (l & 15);
  const int br = (wc << 6) + (l & 15);

  const int nK = K >> 5;
  for (int kt = 0; kt < nK; ++kt) {
    const int kb = kt << 5;
    gload_lds16(A + aoff0 + kb, ldsA);
    gload_lds16(A + aoff0 + ((size_t)K << 6) + kb, ldsA + 2048);
    gload_lds16(Bt + boff0 + kb, ldsB);
    gload_lds16(Bt + boff0 + ((size_t)K << 6) + kb, ldsB + 2048);
    __syncthreads();
    f16x8 af[4], bfr[4];
#pragma unroll
    for (int m = 0; m < 4; ++m) af[m] = *(const f16x8*)(sA + ((ar + (m << 4)) << 5) + ka);
#pragma unroll
    for (int n = 0; n < 4; ++n) bfr[n] = *(const f16x8*)(sB + ((br + (n << 4)) << 5) + ka);
#pragma unroll
    for (int m = 0; m < 4; ++m)
#pragma unroll
      for (int n = 0; n < 4; ++n)
        acc[m][n] = __builtin_amdgcn_mfma_f32_16x16x32_f16(af[m], bfr[n], acc[m][n], 0, 0, 0);
    __syncthreads();
  }

  const int orow = (l >> 4) << 2;
  const int ocol = l & 15;
#pragma unroll
  for (int n = 0; n < 4; ++n) {
    const int gn = n0 + (wc << 6) + (n << 4) + ocol;
    const float bs = BIAS ? bias[gn] : 0.f;
#pragma unroll
    for (int m = 0; m < 4; ++m) {
      const int gm = m0 + (wr << 6) + (m << 4) + orow;
#pragma unroll
      for (int j = 0; j < 4; ++j) {
        C[(size_t)(gm + j) * N + gn] = (OutT)(acc[m][n][j] + bs);
      }
    }
  }
}

// ---------------- 256^2 GEMM v6: 8-phase template (m201 port), BK=64, dbuf ----------------
// C[M][N] = A[M][K]*Bt[N][K]^T + bias. 8 waves (2Mx4N), 16x16x32 MFMA.
// Per K-tile (BK=64), 4 phases, each {ds_read subtile; BAR; LGKM0+schedbar;
// setprio(1); 16 MFMA; setprio(0); BAR}. Quadrants: (m0-3,n0-1) (m0-3,n2-3)
// (m4-7,n0-1) (m4-7,n2-3). All 8 stage gloads of tile tt+1 issued at phase 0
// (4-phase lead >> vmem latency); single VMCNT(0) at tile end -> loads span all
// intra-tile barriers, wait is ~free. Buffer hazard: stage(tt+2) at ph0 of tt+1
// writes buf[tt&1]; all reads of it completed before the tile-end barrier.
// LDS: buffer = A[256][64] + B[256][64] f16 (64 KB), chunk XOR swizzle
// chunk ^= row&7 pre-applied on gload SOURCE, applied on ds_read (involution):
// per quarter-wave, 8 chunks x 2 lanes = all 32 banks x 2-way = conflict-free.

__device__ __forceinline__ void stage64(const f16_t* __restrict__ g, int K,
                                        f16_t* ldsOp, int w, int l) {
  // full operand tile 256 rows x 64 f16 = 32 KB = 4 x (512 thr x 16 B)
#pragma unroll
  for (int i = 0; i < 4; ++i) {
    const int f = i * 512 + w * 64 + l;
    const int row = f >> 3;
    const int ch = (f & 7) ^ (row & 7);  // pre-swizzled source chunk
    gload_lds16(g + (size_t)row * K + (ch << 3), ldsOp + i * 4096 + w * 512);
  }
}

__global__ __launch_bounds__(512, 2) void gemm256_kernel(const f16_t* __restrict__ A,
                                                         const f16_t* __restrict__ Bt,
                                                         float* __restrict__ C,
                                                         const float* __restrict__ bias,
                                                         int M, int N, int K) {
  __shared__ __align__(16) f16_t lds[2 * 32768];  // 2 bufs x (A 32KB + B 32KB) = 128 KB
  const int tid = threadIdx.x;
  const int l = tid & 63;
  const int w = tid >> 6;
  const int wr = w >> 2;
  const int wc = w & 3;
  const int lr = l & 15;
  const int q = l >> 4;

  const int cpx = (int)gridDim.x >> 3;
  const int swzb = ((int)blockIdx.x & 7) * cpx + ((int)blockIdx.x >> 3);
  const int nNT = N >> 8;
  const int mt = swzb / nNT;
  const int nt = swzb % nNT;
  const int m0 = mt << 8;
  const int n0 = nt << 8;

  const f16_t* Apanel = A + (size_t)m0 * K;
  const f16_t* Bpanel = Bt + (size_t)n0 * K;

  // per-lane swizzled chunk indices: logical chunk (kk*4+q) XOR (row&7 == lr&7)
  const int s0 = q ^ (lr & 7);        // kk = 0
  const int s1 = (4 + q) ^ (lr & 7);  // kk = 1
  const int arow = (wr << 7) + lr;
  const int brow = (wc << 6) + lr;
  const int aoff0 = arow * 64 + s0 * 8;        // + m*1024 (+4096 for m4-7)
  const int aoff1 = arow * 64 + s1 * 8;
  const int boff0 = 16384 + brow * 64 + s0 * 8;  // + n*1024
  const int boff1 = 16384 + brow * 64 + s1 * 8;

  f32x4 acc[8][4];
#pragma unroll
  for (int m = 0; m < 8; ++m)
#pragma unroll
    for (int n = 0; n < 4; ++n) acc[m][n] = f32x4{0.f, 0.f, 0.f, 0.f};

  const int NT = K >> 6;  // 16

  // prologue: stage tile 0 into buf 0
  stage64(Apanel, K, lds, w, l);
  stage64(Bpanel, K, lds + 16384, w, l);
  VMCNT(0);
  BARX();

  for (int tt = 0; tt < NT; ++tt) {
    f16_t* cur = lds + (tt & 1) * 32768;
    f16_t* nxt = lds + ((tt + 1) & 1) * 32768;

    f16x8 a0[4][2], a1[4][2], b0[2][2], b1[2][2];

    // ---- phase 0: stage tile tt+1; read a0 (m0-3) + b0 (n0-1); MFMA Q(0,0) ----
    if (tt + 1 < NT) {
      stage64(Apanel + ((size_t)(tt + 1) << 6), K, nxt, w, l);
      stage64(Bpanel + ((size_t)(tt + 1) << 6), K, nxt + 16384, w, l);
    }
#pragma unroll
    for (int m = 0; m < 4; ++m) {
      a0[m][0] = *(const f16x8*)(cur + aoff0 + m * 1024);
      a0[m][1] = *(const f16x8*)(cur + aoff1 + m * 1024);
    }
#pragma unroll
    for (int n = 0; n < 2; ++n) {
      b0[n][0] = *(const f16x8*)(cur + boff0 + n * 1024);
      b0[n][1] = *(const f16x8*)(cur + boff1 + n * 1024);
    }
    BARX();
    LGKM0();
    SCHEDB0();
    __builtin_amdgcn_s_setprio(1);
#pragma unroll
    for (int m = 0; m < 4; ++m)
#pragma unroll
      for (int n = 0; n < 2; ++n) {
        acc[m][n] = __builtin_amdgcn_mfma_f32_16x16x32_f16(a0[m][0], b0[n][0], acc[m][n], 0, 0, 0);
        acc[m][n] = __builtin_amdgcn_mfma_f32_16x16x32_f16(a0[m][1], b0[n][1], acc[m][n], 0, 0, 0);
      }
    __builtin_amdgcn_s_setprio(0);
    BARX();

    // ---- phase 1: read b1 (n2-3); MFMA Q(0,1) ----
#pragma unroll
    for (int n = 0; n < 2; ++n) {
      b1[n][0] = *(const f16x8*)(cur + boff0 + (n + 2) * 1024);
      b1[n][1] = *(const f16x8*)(cur + boff1 + (n + 2) * 1024);
    }
    BARX();
    LGKM0();
    SCHEDB0();
    __builtin_amdgcn_s_setprio(1);
#pragma unroll
    for (int m = 0; m < 4; ++m)
#pragma unroll
      for (int n = 0; n < 2; ++n) {
        acc[m][n + 2] = __builtin_amdgcn_mfma_f32_16x16x32_f16(a0[m][0], b1[n][0], acc[m][n + 2], 0, 0, 0);
        acc[m][n + 2] = __builtin_amdgcn_mfma_f32_16x16x32_f16(a0[m][1], b1[n][1], acc[m][n + 2], 0, 0, 0);
      }
    __builtin_amdgcn_s_setprio(0);
    BARX();

    // ---- phase 2: read a1 (m4-7); MFMA Q(1,0) ----
#pragma unroll
    for (int m = 0; m < 4; ++m) {
      a1[m][0] = *(const f16x8*)(cur + aoff0 + 4096 + m * 1024);
      a1[m][1] = *(const f16x8*)(cur + aoff1 + 4096 + m * 1024);
    }
    BARX();
    LGKM0();
    SCHEDB0();
    __builtin_amdgcn_s_setprio(1);
#pragma unroll
    for (int m = 0; m < 4; ++m)
#pragma unroll
      for (int n = 0; n < 2; ++n) {
        acc[m + 4][n] = __builtin_amdgcn_mfma_f32_16x16x32_f16(a1[m][0], b0[n][0], acc[m + 4][n], 0, 0, 0);
        acc[m + 4][n] = __builtin_amdgcn_mfma_f32_16x16x32_f16(a1[m][1], b0[n][1], acc[m + 4][n], 0, 0, 0);
      }
    __builtin_amdgcn_s_setprio(0);
    BARX();

    // ---- phase 3: MFMA Q(1,1); tile-end vmcnt + barrier ----
    __builtin_amdgcn_s_setprio(1);
#pragma unroll
    for (int m = 0; m < 4; ++m)
#pragma unroll
      for (int n = 0; n < 2; ++n) {
        acc[m + 4][n + 2] = __builtin_amdgcn_mfma_f32_16x16x32_f16(a1[m][0], b1[n][0], acc[m + 4][n + 2], 0, 0, 0);
        acc[m + 4][n + 2] = __builtin_amdgcn_mfma_f32_16x16x32_f16(a1[m][1], b1[n][1], acc[m + 4][n + 2], 0, 0, 0);
      }
    __builtin_amdgcn_s_setprio(0);
    VMCNT(0);  // stage(tt+1) landed (issued ~3 phases ago -> near-zero wait)
    BARX();
  }

  // epilogue: C/D layout col = l&15, row = (l>>4)*4 + j
  float bs[4];
#pragma unroll
  for (int n = 0; n < 4; ++n) bs[n] = bias[n0 + (wc << 6) + (n << 4) + lr];
#pragma unroll
  for (int m = 0; m < 8; ++m) {
    const int gm = m0 + (wr << 7) + (m << 4) + (q << 2);
#pragma unroll
    for (int j = 0; j < 4; ++j) {
      float* Crow = C + (size_t)(gm + j) * N + n0 + (wc << 6) + lr;
#pragma unroll
      for (int n = 0; n < 4; ++n) Crow[n << 4] = acc[m][n][j] + bs[n];
    }
  }
}

// ---------------- launch ----------------

extern "C" void kernel_launch(void* const* d_in, const int* in_sizes, int n_in,
                              void* d_out, int out_size, void* d_ws, size_t ws_size,
                              hipStream_t stream) {
  const float* x = (const float*)d_in[0];    // [8,4096,1024]
  const float* Wv = (const float*)d_in[1];   // [1024,1024]
  const float* bv = (const float*)d_in[2];   // [1024]
  const float* Wo = (const float*)d_in[3];   // [1024,1024]
  const float* bo = (const float*)d_in[4];   // [1024]
  const float* nw = (const float*)d_in[5];   // [3]
  float* out = (float*)d_out;

  char* ws = (char*)d_ws;
  f16_t* Wo_h = (f16_t*)(ws);                  // 2 MB
  f16_t* WvT  = (f16_t*)(ws + (2u << 20));     // 2 MB
  f16_t* WcT  = (f16_t*)(ws + (4u << 20));     // 2 MB (WcT = Wo @ Wv, [e][c])
  float* bc   = (float*)(ws + (6u << 20));     // 4 KB
  f16_t* Xavg = (f16_t*)(ws + (8u << 20));     // 64 MB

  prep_xavg_kernel<<<dim3(7168), dim3(256), 0, stream>>>(
      x, Wo, Wv, bv, bo, nw, in_sizes[5], Wo_h, WvT, bc, Xavg);
  gemm_bt_kernel<f16_t, false><<<dim3(64), dim3(256), 0, stream>>>(
      Wo_h, WvT, WcT, (const float*)nullptr, 1024, 1024, 1024);
  gemm256_kernel<<<dim3(512), dim3(512), 0, stream>>>(
      Xavg, WcT, out, bc, 32768, 1024, 1024);
}